// Round 1
// baseline (598.303 us; speedup 1.0000x reference)
//
#include <hip/hip_runtime.h>

// ---------------------------------------------------------------------------
// Block = x + attn(ln1(x)); x = x + attn(ln2(x))   (attn twice, no MLP,
// no causal mask, softmax scale = C^-0.5).  B=4 T=2048 C=768 H=12 hd=64.
// R11 = R10 (384.8 us) + attn de-staging:
//  - K/V LDS staging dropped: fragment read patterns map 1:1 onto the global
//    layouts K (bh,t,d) / V^T (bh,d,t), all 4 waves read identical K/V
//    addresses -> L1/L2-served.  48 bh % 8 XCDs == 0 -> all qt-blocks of a
//    bh share an XCD; 6 bh x 512 KB = 3 MB < 4 MB per-XCD L2.
//  - kernel is now barrier-free (Ps is wave-private, DS in-order per wave).
//  - 16 K/V fragments single-buffered in regs; next-chunk K loads issued
//    after S-phase, V loads after PV -> ~400 wave-cyc to cover ~200cyc L2.
// attn MFMA/exp2/pack/epilogue logic byte-identical to R10.
// ---------------------------------------------------------------------------

using bf16x8 = __attribute__((ext_vector_type(8))) short;   // 8 bf16 = 4 VGPRs
using f32x4  = __attribute__((ext_vector_type(4))) float;

__device__ __forceinline__ unsigned short f2b(float f) {
  unsigned u = __builtin_bit_cast(unsigned, f);
  u += 0x7FFFu + ((u >> 16) & 1u);          // RNE
  return (unsigned short)(u >> 16);
}
// pack two floats -> two bf16 (RNE) in one dword: lo=a, hi=b
__device__ __forceinline__ unsigned pk2(float a, float b) {
  unsigned ua = __builtin_bit_cast(unsigned, a);
  ua += 0x7FFFu + ((ua >> 16) & 1u);
  unsigned ub = __builtin_bit_cast(unsigned, b);
  ub += 0x7FFFu + ((ub >> 16) & 1u);
  return (ua >> 16) | (ub & 0xFFFF0000u);
}
// truncating pack (for P: downward bias cancels between O-numerator and l)
__device__ __forceinline__ unsigned pk2t(float a, float b) {
  return (__builtin_bit_cast(unsigned, a) >> 16) |
         (__builtin_bit_cast(unsigned, b) & 0xFFFF0000u);
}

#define ASYNC16(g, l)                                                        \
  __builtin_amdgcn_global_load_lds(                                          \
      (const __attribute__((address_space(1))) void*)(g),                    \
      (__attribute__((address_space(3))) void*)(l), 16, 0, 0)

// ---------------------------------------------------------------------------
// Weight transpose+cast: w (768, N) fp32  ->  wt (N, 768) bf16
// ---------------------------------------------------------------------------
__global__ __launch_bounds__(256) void wt_kernel(const float* __restrict__ w,
                                                 unsigned short* __restrict__ wt,
                                                 int N) {
  __shared__ float tile[32][33];
  const int n0 = blockIdx.x * 32, k0 = blockIdx.y * 32;
  const int tx = threadIdx.x, ty = threadIdx.y;  // (32, 8)
#pragma unroll
  for (int i = 0; i < 32; i += 8)
    tile[ty + i][tx] = w[(size_t)(k0 + ty + i) * N + n0 + tx];
  __syncthreads();
#pragma unroll
  for (int i = 0; i < 32; i += 8)
    wt[(size_t)(n0 + ty + i) * 768 + k0 + tx] = f2b(tile[tx][ty + i]);
}

// ---------------------------------------------------------------------------
// LayerNorm: x (8192, 768) fp32 -> h bf16.  One block per row.
// ---------------------------------------------------------------------------
__global__ __launch_bounds__(256) void ln_kernel(const float* __restrict__ x,
                                                 const float* __restrict__ g,
                                                 const float* __restrict__ b,
                                                 unsigned short* __restrict__ h) {
  __shared__ float red[8];
  const int row = blockIdx.x;
  const int tid = threadIdx.x;
  const float* xr = x + (size_t)row * 768;
  float v0 = xr[tid], v1 = xr[tid + 256], v2 = xr[tid + 512];
  float s = v0 + v1 + v2;
  float s2 = v0 * v0 + v1 * v1 + v2 * v2;
#pragma unroll
  for (int off = 1; off < 64; off <<= 1) {
    s += __shfl_xor(s, off);
    s2 += __shfl_xor(s2, off);
  }
  if ((tid & 63) == 0) { red[tid >> 6] = s; red[4 + (tid >> 6)] = s2; }
  __syncthreads();
  const float S  = red[0] + red[1] + red[2] + red[3];
  const float S2 = red[4] + red[5] + red[6] + red[7];
  const float mu  = S * (1.0f / 768.0f);
  const float var = S2 * (1.0f / 768.0f) - mu * mu;
  const float inv = rsqrtf(var + 1e-5f);
  unsigned short* hr = h + (size_t)row * 768;
  hr[tid]       = f2b((v0 - mu) * inv * g[tid] + b[tid]);
  hr[tid + 256] = f2b((v1 - mu) * inv * g[tid + 256] + b[tid + 256]);
  hr[tid + 512] = f2b((v2 - mu) * inv * g[tid + 512] + b[tid + 512]);
}

// ---------------------------------------------------------------------------
// bf16 GEMM, m97 pattern: A (M,768) bf16 row-major, Bt (N,768) bf16,
// 128x128 tile, BK=32, 4 waves x 4x4 mfma tiles.
// EPI 0: scatter qkv (+bias): q (scaled by c2), k -> (bh,t,d) b16 stores;
//        v -> V^T (bh,d,t) with PACKED b64 stores (r values are t-contig).
// EPI 1: out fp32 = resid + bias + acc.
// ---------------------------------------------------------------------------
template <int EPI>
__global__ __launch_bounds__(256, 2) void gemm_kernel(
    const unsigned short* __restrict__ A, const unsigned short* __restrict__ Bt,
    const float* __restrict__ bias, const float* __restrict__ resid,
    unsigned short* __restrict__ q, unsigned short* __restrict__ k,
    unsigned short* __restrict__ vt, float* __restrict__ outF) {
  __shared__ alignas(16) unsigned short As[128 * 32];
  __shared__ alignas(16) unsigned short Bs[128 * 32];

  const int tid = threadIdx.x;
  const int wv = tid >> 6;
  const int lane = tid & 63;
  const int quad = lane >> 4;
  const int l15 = lane & 15;
  const int m0 = blockIdx.y * 128;
  const int n0 = blockIdx.x * 128;

  const int o0 = wv * 1024 + lane * 16;
  const int rT0 = o0 >> 6, c0 = (o0 & 63) >> 1;
  const int o1 = o0 + 4096;
  const int rT1 = o1 >> 6, c1 = (o1 & 63) >> 1;

  const unsigned short* gA0 = A + (size_t)(m0 + rT0) * 768 + c0;
  const unsigned short* gA1 = A + (size_t)(m0 + rT1) * 768 + c1;
  const unsigned short* gB0 = Bt + (size_t)(n0 + rT0) * 768 + c0;
  const unsigned short* gB1 = Bt + (size_t)(n0 + rT1) * 768 + c1;
  unsigned short* lA0 = &As[wv * 512];
  unsigned short* lA1 = &As[wv * 512 + 2048];
  unsigned short* lB0 = &Bs[wv * 512];
  unsigned short* lB1 = &Bs[wv * 512 + 2048];

  f32x4 acc[4][4];
#pragma unroll
  for (int i = 0; i < 4; ++i)
#pragma unroll
    for (int j = 0; j < 4; ++j) acc[i][j] = {0.f, 0.f, 0.f, 0.f};

  const int mBase = (wv >> 1) * 64;
  const int nBase = (wv & 1) * 64;

  for (int kk = 0; kk < 24; ++kk) {
    const int ko = kk * 32;
    ASYNC16(gA0 + ko, lA0);
    ASYNC16(gA1 + ko, lA1);
    ASYNC16(gB0 + ko, lB0);
    ASYNC16(gB1 + ko, lB1);
    __syncthreads();
    bf16x8 af[4], bfv[4];
#pragma unroll
    for (int mt = 0; mt < 4; ++mt)
      af[mt] = *(const bf16x8*)&As[(mBase + mt * 16 + l15) * 32 + quad * 8];
#pragma unroll
    for (int nt = 0; nt < 4; ++nt)
      bfv[nt] = *(const bf16x8*)&Bs[(nBase + nt * 16 + l15) * 32 + quad * 8];
#pragma unroll
    for (int mt = 0; mt < 4; ++mt)
#pragma unroll
      for (int nt = 0; nt < 4; ++nt)
        acc[mt][nt] = __builtin_amdgcn_mfma_f32_16x16x32_bf16(af[mt], bfv[nt],
                                                              acc[mt][nt], 0, 0, 0);
    __syncthreads();
  }

  if constexpr (EPI == 0) {
    const float c2 = 0.052062786090587f;  // 768^-0.5 * log2(e), folded into Q
#pragma unroll
    for (int mt = 0; mt < 4; ++mt) {
#pragma unroll
      for (int nt = 0; nt < 4; ++nt) {
        const int n = n0 + nBase + nt * 16 + l15;
        const int head = n / 192;
        const int rem = n - head * 192;
        const int sel = rem >> 6;
        const int d = rem & 63;
        const float bv = bias[n];
        const int mr = m0 + mBase + mt * 16 + quad * 4;   // r=0 row
        const int bb = mr >> 11;
        const int t = mr & 2047;
        if (sel == 2) {
          // V^T (bh,d,t): 4 r-values are t-contiguous -> one b64 store
          const unsigned long long pk =
              (unsigned long long)pk2(acc[mt][nt][0] + bv, acc[mt][nt][1] + bv) |
              ((unsigned long long)pk2(acc[mt][nt][2] + bv, acc[mt][nt][3] + bv) << 32);
          *(unsigned long long*)&vt[(((size_t)bb * 12 + head) * 64 + d) * 2048 + t] = pk;
        } else {
          unsigned short* tgt = (sel == 0) ? q : k;
          const float sc = (sel == 0) ? c2 : 1.0f;
#pragma unroll
          for (int r = 0; r < 4; ++r)
            tgt[(((size_t)bb * 12 + head) * 2048 + t + r) * 64 + d] =
                f2b((acc[mt][nt][r] + bv) * sc);
        }
      }
    }
  } else {
#pragma unroll
    for (int mt = 0; mt < 4; ++mt) {
#pragma unroll
      for (int nt = 0; nt < 4; ++nt) {
        const int n = n0 + nBase + nt * 16 + l15;
        const float bv = bias[n];
#pragma unroll
        for (int r = 0; r < 4; ++r) {
          const int m = m0 + mBase + mt * 16 + quad * 4 + r;
          const size_t idx = (size_t)m * 768 + n;
          outF[idx] = resid[idx] + bv + acc[mt][nt][r];
        }
      }
    }
  }
}

// ---------------------------------------------------------------------------
// Flash attention (R11 body): role-swapped MFMA, barrier-free, K/V fragments
// read directly from global (L2-resident, XCD-local), Ps wave-private LDS.
//   S^T = K Q^T (Q pre-scaled by c2) -> P = exp2(S^T) packed b64 ->
//   O^T = V^T P^T, l = ones P^T.  Fixed-max softmax (scores ~|2|).
// ---------------------------------------------------------------------------
#define PAD 68
__global__ __launch_bounds__(256, 3) void attn_kernel(
    const unsigned short* __restrict__ Q, const unsigned short* __restrict__ Km,
    const unsigned short* __restrict__ Vt, unsigned short* __restrict__ Y) {
  __shared__ alignas(16) unsigned short Ps[4][32 * PAD];   // wave-private P[q][t]

  const int bh = blockIdx.x;
  const int qt = blockIdx.y;
  const int tid = threadIdx.x;
  const int wv = tid >> 6;
  const int lane = tid & 63;
  const int quad = lane >> 4;
  const int l15 = lane & 15;
  const size_t bhT = (size_t)bh * 2048;

  bf16x8 qf[2][2];
#pragma unroll
  for (int g = 0; g < 2; ++g) {
    const unsigned short* qb = Q + (bhT + qt * 128 + wv * 32 + g * 16 + l15) * 64;
    qf[g][0] = *(const bf16x8*)(qb + quad * 8);
    qf[g][1] = *(const bf16x8*)(qb + 32 + quad * 8);
  }

  f32x4 o[4][2], ol[2];   // o[dt][g] = O^T accum (row=d, col=q)
#pragma unroll
  for (int dt = 0; dt < 4; ++dt)
#pragma unroll
    for (int g = 0; g < 2; ++g) o[dt][g] = {0.f, 0.f, 0.f, 0.f};
  ol[0] = {0.f, 0.f, 0.f, 0.f};
  ol[1] = {0.f, 0.f, 0.f, 0.f};
  const bf16x8 ones = {0x3F80, 0x3F80, 0x3F80, 0x3F80,
                       0x3F80, 0x3F80, 0x3F80, 0x3F80};  // bf16 1.0 x8

  // per-lane K/V fragment base pointers (identical element mapping to the
  // R10 LDS-staged reads; the staging was a pure copy, no transpose):
  //   kf[tt][h] = K[bh][c*64 + tt*16 + l15][h*32 + quad*8 ..+8]
  //   vf[dt][h] = V^T[bh][dt*16 + l15][c*64 + h*32 + quad*8 ..+8]
  const unsigned short* pK = Km + (bhT + l15) * 64 + quad * 8;
  const unsigned short* pV = Vt + ((size_t)bh * 64 + l15) * 2048 + quad * 8;

  bf16x8 kf[4][2], vf[4][2];
#pragma unroll
  for (int tt = 0; tt < 4; ++tt) {
    kf[tt][0] = *(const bf16x8*)(pK + tt * 1024);
    kf[tt][1] = *(const bf16x8*)(pK + tt * 1024 + 32);
  }
#pragma unroll
  for (int dt = 0; dt < 4; ++dt) {
    vf[dt][0] = *(const bf16x8*)(pV + (size_t)dt * 32768);
    vf[dt][1] = *(const bf16x8*)(pV + (size_t)dt * 32768 + 32);
  }

  for (int c = 0; c < 32; ++c) {
    // ---- S^T = K Q^T: 16 MFMAs, 8 independent accumulators ----
    f32x4 s[2][4];
#pragma unroll
    for (int tt = 0; tt < 4; ++tt) {
      s[0][tt] = {0.f, 0.f, 0.f, 0.f};
      s[1][tt] = {0.f, 0.f, 0.f, 0.f};
      s[0][tt] = __builtin_amdgcn_mfma_f32_16x16x32_bf16(kf[tt][0], qf[0][0], s[0][tt], 0, 0, 0);
      s[1][tt] = __builtin_amdgcn_mfma_f32_16x16x32_bf16(kf[tt][0], qf[1][0], s[1][tt], 0, 0, 0);
      s[0][tt] = __builtin_amdgcn_mfma_f32_16x16x32_bf16(kf[tt][1], qf[0][1], s[0][tt], 0, 0, 0);
      s[1][tt] = __builtin_amdgcn_mfma_f32_16x16x32_bf16(kf[tt][1], qf[1][1], s[1][tt], 0, 0, 0);
    }

    // ---- prefetch K for c+1 (last kf use was above; lands during exp+PV) --
    if (c < 31) {
      const unsigned short* pKn = pK + (size_t)(c + 1) * 4096;
#pragma unroll
      for (int tt = 0; tt < 4; ++tt) {
        kf[tt][0] = *(const bf16x8*)(pKn + tt * 1024);
        kf[tt][1] = *(const bf16x8*)(pKn + tt * 1024 + 32);
      }
    }

    // ---- P = exp2(S) (scale pre-folded into Q); truncating b64 pack ----
#pragma unroll
    for (int g = 0; g < 2; ++g)
#pragma unroll
      for (int tt = 0; tt < 4; ++tt) {
        const float e0 = __builtin_amdgcn_exp2f(s[g][tt][0]);
        const float e1 = __builtin_amdgcn_exp2f(s[g][tt][1]);
        const float e2 = __builtin_amdgcn_exp2f(s[g][tt][2]);
        const float e3 = __builtin_amdgcn_exp2f(s[g][tt][3]);
        const unsigned long long pk =
            (unsigned long long)pk2t(e0, e1) |
            ((unsigned long long)pk2t(e2, e3) << 32);
        *(unsigned long long*)&Ps[wv][(g * 16 + l15) * PAD + tt * 16 + quad * 4] = pk;
      }
    // no barrier: Ps[wv] is wave-private, DS ops are in-order per wave

    // ---- O^T += V^T P^T,  l += ones P^T ----
#pragma unroll
    for (int ks = 0; ks < 2; ++ks) {
      bf16x8 pf0 = *(const bf16x8*)&Ps[wv][(l15) * PAD + ks * 32 + quad * 8];
      bf16x8 pf1 = *(const bf16x8*)&Ps[wv][(16 + l15) * PAD + ks * 32 + quad * 8];
      ol[0] = __builtin_amdgcn_mfma_f32_16x16x32_bf16(ones, pf0, ol[0], 0, 0, 0);
      ol[1] = __builtin_amdgcn_mfma_f32_16x16x32_bf16(ones, pf1, ol[1], 0, 0, 0);
#pragma unroll
      for (int dt = 0; dt < 4; ++dt) {
        o[dt][0] = __builtin_amdgcn_mfma_f32_16x16x32_bf16(vf[dt][ks], pf0, o[dt][0], 0, 0, 0);
        o[dt][1] = __builtin_amdgcn_mfma_f32_16x16x32_bf16(vf[dt][ks], pf1, o[dt][1], 0, 0, 0);
      }
    }

    // ---- prefetch V for c+1 (last vf use was above; lands during next S) --
    if (c < 31) {
      const unsigned short* pVn = pV + (c + 1) * 64;
#pragma unroll
      for (int dt = 0; dt < 4; ++dt) {
        vf[dt][0] = *(const bf16x8*)(pVn + (size_t)dt * 32768);
        vf[dt][1] = *(const bf16x8*)(pVn + (size_t)dt * 32768 + 32);
      }
    }
  }

  // ---- epilogue: O^T is d-contiguous per lane -> direct b64 Y stores ----
  const int b = bh / 12;
  const int head = bh - b * 12;
#pragma unroll
  for (int g = 0; g < 2; ++g) {
    const float rl = 1.0f / ol[g][0];
    const int row = qt * 128 + wv * 32 + g * 16 + l15;
    unsigned short* yb = Y + ((size_t)(b * 2048 + row)) * 768 + head * 64;
#pragma unroll
    for (int dt = 0; dt < 4; ++dt) {
      const unsigned long long pk =
          (unsigned long long)pk2(o[dt][g][0] * rl, o[dt][g][1] * rl) |
          ((unsigned long long)pk2(o[dt][g][2] * rl, o[dt][g][3] * rl) << 32);
      *(unsigned long long*)(yb + dt * 16 + quad * 4) = pk;
    }
  }
}

// ---------------------------------------------------------------------------
extern "C" void kernel_launch(void* const* d_in, const int* in_sizes, int n_in,
                              void* d_out, int out_size, void* d_ws, size_t ws_size,
                              hipStream_t stream) {
  const float* x      = (const float*)d_in[0];
  const float* w_attn = (const float*)d_in[1];
  const float* b_attn = (const float*)d_in[2];
  const float* w_proj = (const float*)d_in[3];
  const float* b_proj = (const float*)d_in[4];
  const float* ln_g[2] = {(const float*)d_in[5], (const float*)d_in[7]};
  const float* ln_b[2] = {(const float*)d_in[6], (const float*)d_in[8]};
  float* out = (float*)d_out;

  unsigned short* wAt = (unsigned short*)d_ws;     // (2304,768) bf16
  unsigned short* wPt = wAt + 2304 * 768;          // (768,768)  bf16
  unsigned short* h   = wPt + 768 * 768;           // (8192,768) bf16
  unsigned short* q   = h + 8192 * 768;            // (48,2048,64)
  unsigned short* k   = q + 48 * 2048 * 64;
  unsigned short* vt  = k + 48 * 2048 * 64;        // (48,64,2048) = V^T
  unsigned short* y   = vt + 48 * 2048 * 64;       // (8192,768) bf16

  wt_kernel<<<dim3(72, 24), dim3(32, 8), 0, stream>>>(w_attn, wAt, 2304);
  wt_kernel<<<dim3(24, 24), dim3(32, 8), 0, stream>>>(w_proj, wPt, 768);

  for (int pass = 0; pass < 2; ++pass) {
    const float* xin = pass ? (const float*)out : x;
    ln_kernel<<<8192, 256, 0, stream>>>(xin, ln_g[pass], ln_b[pass], h);
    gemm_kernel<0><<<dim3(18, 64), 256, 0, stream>>>(h, wAt, b_attn, nullptr,
                                                     q, k, vt, nullptr);
    attn_kernel<<<dim3(48, 16), 256, 0, stream>>>(q, k, vt, y);
    gemm_kernel<1><<<dim3(6, 64), 256, 0, stream>>>(y, wPt, b_proj, xin,
                                                    nullptr, nullptr, nullptr, out);
  }
}

// Round 2
// 386.566 us; speedup vs baseline: 1.5477x; 1.5477x over previous
//
#include <hip/hip_runtime.h>

// ---------------------------------------------------------------------------
// Block = x + attn(ln1(x)); x = x + attn(ln2(x))   (attn twice, no MLP,
// no causal mask, softmax scale = C^-0.5).  B=4 T=2048 C=768 H=12 hd=64.
// R12 = R10 (384.8us) with attn rebuilt around 32x32x16 MFMA:
//  - P stays in registers: S-tile C-layout -> PV B-frag via 4
//    v_permlane32_swap_b32 per 32x32 tile (no Ps LDS round-trip).
//  - K/V staged by global_load_lds (width16) into linear LDS with
//    pre-swizzled global source; reads XOR ((row&7)<<4) -> conflict-free.
//  - l accumulated in VALU from truncated bf16 P (same numerics as R10's
//    ones-MFMA on truncated P).
//  - same 1-barrier/chunk dbuf schedule as R10 (proven); DS per wave/chunk
//    drops 28KB -> 16KB, MFMA instrs halve.
// ---------------------------------------------------------------------------

using bf16x8 = __attribute__((ext_vector_type(8))) short;   // 8 bf16 = 4 VGPRs
using f32x4  = __attribute__((ext_vector_type(4))) float;
using f32x16 = __attribute__((ext_vector_type(16))) float;

__device__ __forceinline__ unsigned short f2b(float f) {
  unsigned u = __builtin_bit_cast(unsigned, f);
  u += 0x7FFFu + ((u >> 16) & 1u);          // RNE
  return (unsigned short)(u >> 16);
}
// pack two floats -> two bf16 (RNE) in one dword: lo=a, hi=b
__device__ __forceinline__ unsigned pk2(float a, float b) {
  unsigned ua = __builtin_bit_cast(unsigned, a);
  ua += 0x7FFFu + ((ua >> 16) & 1u);
  unsigned ub = __builtin_bit_cast(unsigned, b);
  ub += 0x7FFFu + ((ub >> 16) & 1u);
  return (ua >> 16) | (ub & 0xFFFF0000u);
}

__device__ __forceinline__ bf16x8 mk8(unsigned a, unsigned b, unsigned c,
                                      unsigned d) {
  union { unsigned u[4]; bf16x8 v; } x;
  x.u[0] = a; x.u[1] = b; x.u[2] = c; x.u[3] = d;
  return x.v;
}

#define ASYNC16(g, l)                                                        \
  __builtin_amdgcn_global_load_lds(                                          \
      (const __attribute__((address_space(1))) void*)(g),                    \
      (__attribute__((address_space(3))) void*)(l), 16, 0, 0)

// swap a.hi32lanes <-> b.lo32lanes (V_PERMLANE32_SWAP_B32)
#define PLSWAP(a, b) asm("v_permlane32_swap_b32 %0, %1" : "+v"(a), "+v"(b))

// ---------------------------------------------------------------------------
// Weight transpose+cast: w (768, N) fp32  ->  wt (N, 768) bf16
// ---------------------------------------------------------------------------
__global__ __launch_bounds__(256) void wt_kernel(const float* __restrict__ w,
                                                 unsigned short* __restrict__ wt,
                                                 int N) {
  __shared__ float tile[32][33];
  const int n0 = blockIdx.x * 32, k0 = blockIdx.y * 32;
  const int tx = threadIdx.x, ty = threadIdx.y;  // (32, 8)
#pragma unroll
  for (int i = 0; i < 32; i += 8)
    tile[ty + i][tx] = w[(size_t)(k0 + ty + i) * N + n0 + tx];
  __syncthreads();
#pragma unroll
  for (int i = 0; i < 32; i += 8)
    wt[(size_t)(n0 + ty + i) * 768 + k0 + tx] = f2b(tile[tx][ty + i]);
}

// ---------------------------------------------------------------------------
// LayerNorm: x (8192, 768) fp32 -> h bf16.  One block per row.
// ---------------------------------------------------------------------------
__global__ __launch_bounds__(256) void ln_kernel(const float* __restrict__ x,
                                                 const float* __restrict__ g,
                                                 const float* __restrict__ b,
                                                 unsigned short* __restrict__ h) {
  __shared__ float red[8];
  const int row = blockIdx.x;
  const int tid = threadIdx.x;
  const float* xr = x + (size_t)row * 768;
  float v0 = xr[tid], v1 = xr[tid + 256], v2 = xr[tid + 512];
  float s = v0 + v1 + v2;
  float s2 = v0 * v0 + v1 * v1 + v2 * v2;
#pragma unroll
  for (int off = 1; off < 64; off <<= 1) {
    s += __shfl_xor(s, off);
    s2 += __shfl_xor(s2, off);
  }
  if ((tid & 63) == 0) { red[tid >> 6] = s; red[4 + (tid >> 6)] = s2; }
  __syncthreads();
  const float S  = red[0] + red[1] + red[2] + red[3];
  const float S2 = red[4] + red[5] + red[6] + red[7];
  const float mu  = S * (1.0f / 768.0f);
  const float var = S2 * (1.0f / 768.0f) - mu * mu;
  const float inv = rsqrtf(var + 1e-5f);
  unsigned short* hr = h + (size_t)row * 768;
  hr[tid]       = f2b((v0 - mu) * inv * g[tid] + b[tid]);
  hr[tid + 256] = f2b((v1 - mu) * inv * g[tid + 256] + b[tid + 256]);
  hr[tid + 512] = f2b((v2 - mu) * inv * g[tid + 512] + b[tid + 512]);
}

// ---------------------------------------------------------------------------
// bf16 GEMM, m97 pattern: A (M,768) bf16 row-major, Bt (N,768) bf16,
// 128x128 tile, BK=32, 4 waves x 4x4 mfma tiles.
// EPI 0: scatter qkv (+bias): q (scaled by c2), k -> (bh,t,d) b16 stores;
//        v -> V^T (bh,d,t) with PACKED b64 stores (r values are t-contig).
// EPI 1: out fp32 = resid + bias + acc.
// ---------------------------------------------------------------------------
template <int EPI>
__global__ __launch_bounds__(256, 2) void gemm_kernel(
    const unsigned short* __restrict__ A, const unsigned short* __restrict__ Bt,
    const float* __restrict__ bias, const float* __restrict__ resid,
    unsigned short* __restrict__ q, unsigned short* __restrict__ k,
    unsigned short* __restrict__ vt, float* __restrict__ outF) {
  __shared__ alignas(16) unsigned short As[128 * 32];
  __shared__ alignas(16) unsigned short Bs[128 * 32];

  const int tid = threadIdx.x;
  const int wv = tid >> 6;
  const int lane = tid & 63;
  const int quad = lane >> 4;
  const int l15 = lane & 15;
  const int m0 = blockIdx.y * 128;
  const int n0 = blockIdx.x * 128;

  const int o0 = wv * 1024 + lane * 16;
  const int rT0 = o0 >> 6, c0 = (o0 & 63) >> 1;
  const int o1 = o0 + 4096;
  const int rT1 = o1 >> 6, c1 = (o1 & 63) >> 1;

  const unsigned short* gA0 = A + (size_t)(m0 + rT0) * 768 + c0;
  const unsigned short* gA1 = A + (size_t)(m0 + rT1) * 768 + c1;
  const unsigned short* gB0 = Bt + (size_t)(n0 + rT0) * 768 + c0;
  const unsigned short* gB1 = Bt + (size_t)(n0 + rT1) * 768 + c1;
  unsigned short* lA0 = &As[wv * 512];
  unsigned short* lA1 = &As[wv * 512 + 2048];
  unsigned short* lB0 = &Bs[wv * 512];
  unsigned short* lB1 = &Bs[wv * 512 + 2048];

  f32x4 acc[4][4];
#pragma unroll
  for (int i = 0; i < 4; ++i)
#pragma unroll
    for (int j = 0; j < 4; ++j) acc[i][j] = {0.f, 0.f, 0.f, 0.f};

  const int mBase = (wv >> 1) * 64;
  const int nBase = (wv & 1) * 64;

  for (int kk = 0; kk < 24; ++kk) {
    const int ko = kk * 32;
    ASYNC16(gA0 + ko, lA0);
    ASYNC16(gA1 + ko, lA1);
    ASYNC16(gB0 + ko, lB0);
    ASYNC16(gB1 + ko, lB1);
    __syncthreads();
    bf16x8 af[4], bfv[4];
#pragma unroll
    for (int mt = 0; mt < 4; ++mt)
      af[mt] = *(const bf16x8*)&As[(mBase + mt * 16 + l15) * 32 + quad * 8];
#pragma unroll
    for (int nt = 0; nt < 4; ++nt)
      bfv[nt] = *(const bf16x8*)&Bs[(nBase + nt * 16 + l15) * 32 + quad * 8];
#pragma unroll
    for (int mt = 0; mt < 4; ++mt)
#pragma unroll
      for (int nt = 0; nt < 4; ++nt)
        acc[mt][nt] = __builtin_amdgcn_mfma_f32_16x16x32_bf16(af[mt], bfv[nt],
                                                              acc[mt][nt], 0, 0, 0);
    __syncthreads();
  }

  if constexpr (EPI == 0) {
    const float c2 = 0.052062786090587f;  // 768^-0.5 * log2(e), folded into Q
#pragma unroll
    for (int mt = 0; mt < 4; ++mt) {
#pragma unroll
      for (int nt = 0; nt < 4; ++nt) {
        const int n = n0 + nBase + nt * 16 + l15;
        const int head = n / 192;
        const int rem = n - head * 192;
        const int sel = rem >> 6;
        const int d = rem & 63;
        const float bv = bias[n];
        const int mr = m0 + mBase + mt * 16 + quad * 4;   // r=0 row
        const int bb = mr >> 11;
        const int t = mr & 2047;
        if (sel == 2) {
          // V^T (bh,d,t): 4 r-values are t-contiguous -> one b64 store
          const unsigned long long pk =
              (unsigned long long)pk2(acc[mt][nt][0] + bv, acc[mt][nt][1] + bv) |
              ((unsigned long long)pk2(acc[mt][nt][2] + bv, acc[mt][nt][3] + bv) << 32);
          *(unsigned long long*)&vt[(((size_t)bb * 12 + head) * 64 + d) * 2048 + t] = pk;
        } else {
          unsigned short* tgt = (sel == 0) ? q : k;
          const float sc = (sel == 0) ? c2 : 1.0f;
#pragma unroll
          for (int r = 0; r < 4; ++r)
            tgt[(((size_t)bb * 12 + head) * 2048 + t + r) * 64 + d] =
                f2b((acc[mt][nt][r] + bv) * sc);
        }
      }
    }
  } else {
#pragma unroll
    for (int mt = 0; mt < 4; ++mt) {
#pragma unroll
      for (int nt = 0; nt < 4; ++nt) {
        const int n = n0 + nBase + nt * 16 + l15;
        const float bv = bias[n];
#pragma unroll
        for (int r = 0; r < 4; ++r) {
          const int m = m0 + mBase + mt * 16 + quad * 4 + r;
          const size_t idx = (size_t)m * 768 + n;
          outF[idx] = resid[idx] + bv + acc[mt][nt][r];
        }
      }
    }
  }
}

// ---------------------------------------------------------------------------
// Flash attention (R12 body): 32x32x16 MFMA, in-register P via permlane
// swaps, K/V via swizzled global_load_lds dbuf, 1 barrier/chunk.
//   S^T = K Q^T (Q pre-scaled by c2) -> P = exp2(S^T) truncated to bf16 in
//   regs -> O^T += V^T P^T ;  l += sum(P) in VALU.  Fixed-max softmax.
// Per wave: 32 q rows, chunk = 64 t.  Block: 4 waves = 128 q.
// ---------------------------------------------------------------------------
__global__ __launch_bounds__(256, 3) void attn_kernel(
    const unsigned short* __restrict__ Q, const unsigned short* __restrict__ Km,
    const unsigned short* __restrict__ Vt, unsigned short* __restrict__ Y) {
  __shared__ alignas(16) unsigned short Ks[2][64 * 64];  // [t][d], swizzled
  __shared__ alignas(16) unsigned short Vs[2][64 * 64];  // [d][t], swizzled

  const int bh   = blockIdx.x;
  const int qt   = blockIdx.y;
  const int tid  = threadIdx.x;
  const int wv   = tid >> 6;
  const int lane = tid & 63;
  const int l31  = lane & 31;
  const int hi   = lane >> 5;
  const int s7   = l31 & 7;
  const size_t bhT = (size_t)bh * 2048;

  // ---- Q fragments: B-operand, lane holds Q[q=l31][d=ks*16+hi*8+j] --------
  bf16x8 qf[4];
  {
    const unsigned short* qb =
        Q + (bhT + qt * 128 + wv * 32 + l31) * 64 + hi * 8;
#pragma unroll
    for (int ks = 0; ks < 4; ++ks) qf[ks] = *(const bf16x8*)(qb + ks * 16);
  }

  // ---- staging: linear LDS dest, inverse-swizzled global source -----------
  // LDS slot L (bytes): row r = L>>7, in-row byte = (L&127) ^ ((r&7)<<4)
  const int L0 = wv * 1024 + (lane << 4);
  const int L1 = L0 + 4096;
  const int r0 = L0 >> 7, b0 = (L0 & 127) ^ ((r0 & 7) << 4);
  const int r1 = L1 >> 7, b1 = (L1 & 127) ^ ((r1 & 7) << 4);
  const unsigned short* kg0 = Km + (bhT + r0) * 64 + (b0 >> 1);
  const unsigned short* kg1 = Km + (bhT + r1) * 64 + (b1 >> 1);
  const unsigned short* vg0 = Vt + ((size_t)bh * 64 + r0) * 2048 + (b0 >> 1);
  const unsigned short* vg1 = Vt + ((size_t)bh * 64 + r1) * 2048 + (b1 >> 1);
  const int kb0 = wv * 512, kb1 = wv * 512 + 2048;  // ushort units

  f32x16 o0, o1;
#pragma unroll
  for (int i = 0; i < 16; ++i) { o0[i] = 0.f; o1[i] = 0.f; }
  float l_acc = 0.f;

  // prologue: stage chunk 0 into buf 0
  ASYNC16(kg0, &Ks[0][kb0]);
  ASYNC16(kg1, &Ks[0][kb1]);
  ASYNC16(vg0, &Vs[0][kb0]);
  ASYNC16(vg1, &Vs[0][kb1]);
  __syncthreads();

  for (int c = 0; c < 32; ++c) {
    const int p = c & 1;
    if (c < 31) {  // stage c+1 into the other buffer; lands by chunk-end sync
      const int ka = (c + 1) * 4096, va = (c + 1) * 64;
      ASYNC16(kg0 + ka, &Ks[p ^ 1][kb0]);
      ASYNC16(kg1 + ka, &Ks[p ^ 1][kb1]);
      ASYNC16(vg0 + va, &Vs[p ^ 1][kb0]);
      ASYNC16(vg1 + va, &Vs[p ^ 1][kb1]);
    }
    const unsigned short* Kp = &Ks[p][0];
    const unsigned short* Vp = &Vs[p][0];

#pragma unroll
    for (int tt = 0; tt < 2; ++tt) {
      // ---- S tile (32t x 32q): 4 chained k-steps ----
      f32x16 s;
#pragma unroll
      for (int i = 0; i < 16; ++i) s[i] = 0.f;
#pragma unroll
      for (int ks = 0; ks < 4; ++ks) {
        const int off = tt * 4096 + l31 * 128 + (((ks * 2 + hi) ^ s7) << 4);
        bf16x8 kf = *(const bf16x8*)&Kp[off >> 1];
        s = __builtin_amdgcn_mfma_f32_32x32x16_bf16(kf, qf[ks], s, 0, 0, 0);
      }

      // ---- P = exp2(S), truncate to bf16; l += truncated values ----
      unsigned dw[8];
      float lc = 0.f;
#pragma unroll
      for (int r2 = 0; r2 < 8; ++r2) {
        const float e0 = __builtin_amdgcn_exp2f(s[2 * r2]);
        const float e1 = __builtin_amdgcn_exp2f(s[2 * r2 + 1]);
        const unsigned u0 = __builtin_bit_cast(unsigned, e0) & 0xFFFF0000u;
        const unsigned u1 = __builtin_bit_cast(unsigned, e1) & 0xFFFF0000u;
        lc += __builtin_bit_cast(float, u0) + __builtin_bit_cast(float, u1);
        dw[r2] = (u0 >> 16) | u1;
      }
      l_acc += lc;

      // ---- C-layout -> B-frag: one swap yields two pf words ----
      PLSWAP(dw[0], dw[2]);
      PLSWAP(dw[1], dw[3]);
      PLSWAP(dw[4], dw[6]);
      PLSWAP(dw[5], dw[7]);
      const bf16x8 pf0 = mk8(dw[0], dw[1], dw[2], dw[3]);  // t in [tt*32, +16)
      const bf16x8 pf1 = mk8(dw[4], dw[5], dw[6], dw[7]);  // t in [+16, +32)

      // ---- O^T += V^T P^T ----
#pragma unroll
      for (int dt = 0; dt < 2; ++dt) {
        const int vb = dt * 4096 + l31 * 128;
        const int kv0 = tt * 2, kv1 = tt * 2 + 1;
        bf16x8 vf0 = *(const bf16x8*)&Vp[(vb + (((kv0 * 2 + hi) ^ s7) << 4)) >> 1];
        bf16x8 vf1 = *(const bf16x8*)&Vp[(vb + (((kv1 * 2 + hi) ^ s7) << 4)) >> 1];
        if (dt == 0) {
          o0 = __builtin_amdgcn_mfma_f32_32x32x16_bf16(vf0, pf0, o0, 0, 0, 0);
          o0 = __builtin_amdgcn_mfma_f32_32x32x16_bf16(vf1, pf1, o0, 0, 0, 0);
        } else {
          o1 = __builtin_amdgcn_mfma_f32_32x32x16_bf16(vf0, pf0, o1, 0, 0, 0);
          o1 = __builtin_amdgcn_mfma_f32_32x32x16_bf16(vf1, pf1, o1, 0, 0, 0);
        }
      }
    }
    __syncthreads();  // waits vmcnt (next-chunk stages landed) + all waves
  }

  // ---- l: add the other 32-lane half's partial ----
  unsigned la = __builtin_bit_cast(unsigned, l_acc), lb = la;
  PLSWAP(la, lb);
  // lanes<32: other half's value is in lb; lanes>=32: in la
  const float l_tot =
      l_acc + __builtin_bit_cast(float, hi ? la : lb);
  const float rl = 1.0f / l_tot;

  // ---- epilogue: O^T regs are 4-d-contiguous -> b64 Y stores ----
  const int b = bh / 12;
  const int head = bh - b * 12;
  const int row = qt * 128 + wv * 32 + l31;
  unsigned short* yb = Y + ((size_t)(b * 2048 + row)) * 768 + head * 64;
#pragma unroll
  for (int dt = 0; dt < 2; ++dt) {
#pragma unroll
    for (int g4 = 0; g4 < 4; ++g4) {
      const int d = dt * 32 + g4 * 8 + hi * 4;
      const float a0 = (dt ? o1[g4 * 4 + 0] : o0[g4 * 4 + 0]) * rl;
      const float a1 = (dt ? o1[g4 * 4 + 1] : o0[g4 * 4 + 1]) * rl;
      const float a2 = (dt ? o1[g4 * 4 + 2] : o0[g4 * 4 + 2]) * rl;
      const float a3 = (dt ? o1[g4 * 4 + 3] : o0[g4 * 4 + 3]) * rl;
      const unsigned long long pk =
          (unsigned long long)pk2(a0, a1) | ((unsigned long long)pk2(a2, a3) << 32);
      *(unsigned long long*)(yb + d) = pk;
    }
  }
}

// ---------------------------------------------------------------------------
extern "C" void kernel_launch(void* const* d_in, const int* in_sizes, int n_in,
                              void* d_out, int out_size, void* d_ws, size_t ws_size,
                              hipStream_t stream) {
  const float* x      = (const float*)d_in[0];
  const float* w_attn = (const float*)d_in[1];
  const float* b_attn = (const float*)d_in[2];
  const float* w_proj = (const float*)d_in[3];
  const float* b_proj = (const float*)d_in[4];
  const float* ln_g[2] = {(const float*)d_in[5], (const float*)d_in[7]};
  const float* ln_b[2] = {(const float*)d_in[6], (const float*)d_in[8]};
  float* out = (float*)d_out;

  unsigned short* wAt = (unsigned short*)d_ws;     // (2304,768) bf16
  unsigned short* wPt = wAt + 2304 * 768;          // (768,768)  bf16
  unsigned short* h   = wPt + 768 * 768;           // (8192,768) bf16
  unsigned short* q   = h + 8192 * 768;            // (48,2048,64)
  unsigned short* k   = q + 48 * 2048 * 64;
  unsigned short* vt  = k + 48 * 2048 * 64;        // (48,64,2048) = V^T
  unsigned short* y   = vt + 48 * 2048 * 64;       // (8192,768) bf16

  wt_kernel<<<dim3(72, 24), dim3(32, 8), 0, stream>>>(w_attn, wAt, 2304);
  wt_kernel<<<dim3(24, 24), dim3(32, 8), 0, stream>>>(w_proj, wPt, 768);

  for (int pass = 0; pass < 2; ++pass) {
    const float* xin = pass ? (const float*)out : x;
    ln_kernel<<<8192, 256, 0, stream>>>(xin, ln_g[pass], ln_b[pass], h);
    gemm_kernel<0><<<dim3(18, 64), 256, 0, stream>>>(h, wAt, b_attn, nullptr,
                                                     q, k, vt, nullptr);
    attn_kernel<<<dim3(48, 16), 256, 0, stream>>>(q, k, vt, y);
    gemm_kernel<1><<<dim3(6, 64), 256, 0, stream>>>(y, wPt, b_proj, xin,
                                                    nullptr, nullptr, nullptr, out);
  }
}